// Round 1
// baseline (360.425 us; speedup 1.0000x reference)
//
#include <hip/hip_runtime.h>

// Problem constants (from reference)
constexpr int C_ = 1000;
constexpr int A_ = 512;
constexpr int N_ = 65536;
constexpr float ONE_MINUS_M = 0.2f;   // 1 - MOMENTUM

// Accum kernel geometry
constexpr int LSTR = 17;              // LDS row stride (pad 16 -> 17 to break bank aliasing)
constexpr int NCHUNK = 8;             // row chunks
constexpr int NCG = 32;               // column groups (A_/16)
constexpr int TPB = 512;
constexpr int ROWS_PER_CHUNK = N_ / NCHUNK;   // 8192
constexpr int ROWS_PER_ITER = TPB / 4;        // 128 rows in flight per step

// Phase 1: per-class sum and sum-of-squares over a 16-column slice,
// accumulated in LDS, flushed to partial buffers (or atomically to a
// single buffer when ws is small).
__global__ __launch_bounds__(TPB) void accum_kernel(
    const float* __restrict__ feat, const int* __restrict__ labels,
    float* __restrict__ pS, float* __restrict__ pQ, int use_partials)
{
    __shared__ float lsum[C_ * LSTR];   // 68 KB
    __shared__ float lsq [C_ * LSTR];   // 68 KB
    for (int i = threadIdx.x; i < C_ * LSTR; i += TPB) { lsum[i] = 0.f; lsq[i] = 0.f; }
    __syncthreads();

    const int cg    = blockIdx.x & (NCG - 1);
    const int chunk = blockIdx.x / NCG;
    const int col0  = cg * 16;
    const int row0  = chunk * ROWS_PER_CHUNK;
    const int rlane = threadIdx.x >> 2;        // 0..127: row within group
    const int csub  = (threadIdx.x & 3) * 4;   // 0,4,8,12: float4 within 16-col slice

    int r = row0 + rlane;
    // 4-deep batched loads for latency hiding, then the LDS atomic burst.
    for (int it = 0; it < ROWS_PER_CHUNK / (4 * ROWS_PER_ITER); ++it) {
        float4 v[4]; int lab[4];
        #pragma unroll
        for (int u = 0; u < 4; ++u) {
            const int rr = r + u * ROWS_PER_ITER;
            lab[u] = labels[rr];
            v[u] = *reinterpret_cast<const float4*>(feat + (size_t)rr * A_ + col0 + csub);
        }
        #pragma unroll
        for (int u = 0; u < 4; ++u) {
            float* ps = &lsum[lab[u] * LSTR + csub];
            float* pq = &lsq [lab[u] * LSTR + csub];
            atomicAdd(ps + 0, v[u].x);        atomicAdd(ps + 1, v[u].y);
            atomicAdd(ps + 2, v[u].z);        atomicAdd(ps + 3, v[u].w);
            atomicAdd(pq + 0, v[u].x * v[u].x); atomicAdd(pq + 1, v[u].y * v[u].y);
            atomicAdd(pq + 2, v[u].z * v[u].z); atomicAdd(pq + 3, v[u].w * v[u].w);
        }
        r += 4 * ROWS_PER_ITER;
    }
    __syncthreads();

    if (use_partials) {
        float* dS = pS + (size_t)chunk * (C_ * A_);
        float* dQ = pQ + (size_t)chunk * (C_ * A_);
        for (int i = threadIdx.x; i < C_ * 16; i += TPB) {
            const int c = i >> 4, p = i & 15;
            dS[c * A_ + col0 + p] = lsum[c * LSTR + p];
            dQ[c * A_ + col0 + p] = lsq [c * LSTR + p];
        }
    } else {
        for (int i = threadIdx.x; i < C_ * 16; i += TPB) {
            const int c = i >> 4, p = i & 15;
            atomicAdd(&pS[c * A_ + col0 + p], lsum[c * LSTR + p]);
            atomicAdd(&pQ[c * A_ + col0 + p], lsq [c * LSTR + p]);
        }
    }
}

// Label histogram -> cnt[c]
__global__ __launch_bounds__(256) void hist_kernel(
    const int* __restrict__ labels, int* __restrict__ cnt)
{
    __shared__ int h[C_];
    for (int i = threadIdx.x; i < C_; i += blockDim.x) h[i] = 0;
    __syncthreads();
    for (int i = blockIdx.x * blockDim.x + threadIdx.x; i < N_; i += gridDim.x * blockDim.x)
        atomicAdd(&h[labels[i]], 1);
    __syncthreads();
    for (int i = threadIdx.x; i < C_; i += blockDim.x)
        if (h[i] != 0) atomicAdd(&cnt[i], h[i]);
}

// Phase 2: reduce partials, apply the EMA update. One thread per (c,a).
// Safe when pS/pQ alias `out` (each thread reads only its own idx first).
__global__ __launch_bounds__(256) void finalize_kernel(
    const float* __restrict__ pS, const float* __restrict__ pQ, int nPart,
    const int* __restrict__ cnt, const float* __restrict__ cov,
    const float* __restrict__ mean, const float* __restrict__ amount,
    float* __restrict__ out)
{
    const int idx = blockIdx.x * blockDim.x + threadIdx.x;
    if (idx >= C_ * A_) return;
    const int c = idx >> 9;   // A_ = 512

    float s = 0.f, q = 0.f;
    for (int rp = 0; rp < nPart; ++rp) {
        s += pS[(size_t)rp * (C_ * A_) + idx];
        q += pQ[(size_t)rp * (C_ * A_) + idx];
    }
    const float cntf = (float)cnt[c];
    const float safe = (cntf == 0.f) ? 1.f : cntf;
    const float ave  = s / safe;
    float var = q / safe - ave * ave;          // == segsum((x-ave)^2)/safe
    var = fmaxf(var, 0.f);

    const float amt   = amount[c];
    const float den   = cntf + amt;
    const float w_raw = (den > 0.f) ? (cntf / den) : 0.f;
    const float w     = (w_raw > 0.f) ? fmaxf(w_raw, ONE_MINUS_M) : 0.f;

    const float m  = mean[idx];
    const float cv = cov[idx];
    const float d  = m - ave;
    out[idx]           = cv * (1.f - w) + var * w + w * (1.f - w) * d * d;  // new_cov
    out[C_ * A_ + idx] = m * (1.f - w) + ave * w;                            // new_mean
}

__global__ __launch_bounds__(256) void amount_kernel(
    const int* __restrict__ cnt, const float* __restrict__ amount, float* __restrict__ out)
{
    const int c = blockIdx.x * blockDim.x + threadIdx.x;
    if (c < C_) out[2 * C_ * A_ + c] = amount[c] + (float)cnt[c];
}

extern "C" void kernel_launch(void* const* d_in, const int* in_sizes, int n_in,
                              void* d_out, int out_size, void* d_ws, size_t ws_size,
                              hipStream_t stream)
{
    const float* feat   = (const float*)d_in[0];
    const int*   labels = (const int*)  d_in[1];
    const float* cov    = (const float*)d_in[2];
    const float* mean   = (const float*)d_in[3];
    const float* amount = (const float*)d_in[4];
    float* out = (float*)d_out;

    const size_t CA = (size_t)C_ * A_;
    const size_t cntBytes  = 4096;                              // cnt[1000] padded
    const size_t partBytes = (size_t)NCHUNK * CA * sizeof(float);

    float *pS, *pQ; int* cnt; int nPart; int use_partials;
    if (ws_size >= cntBytes + 2 * partBytes) {
        // Tier 1: 8 partial buffers in ws — no global atomics, deterministic flush.
        cnt = (int*)d_ws;
        pS  = (float*)((char*)d_ws + cntBytes);
        pQ  = pS + NCHUNK * CA;
        nPart = NCHUNK; use_partials = 1;
        hipMemsetAsync(d_ws, 0, cntBytes, stream);
    } else if (ws_size >= cntBytes + 2 * CA * sizeof(float)) {
        // Tier 2: single accumulator in ws, atomic flush (8 adds/address).
        cnt = (int*)d_ws;
        pS  = (float*)((char*)d_ws + cntBytes);
        pQ  = pS + CA;
        nPart = 1; use_partials = 0;
        hipMemsetAsync(d_ws, 0, cntBytes + 2 * CA * sizeof(float), stream);
    } else {
        // Tier 3: alias accumulators into d_out (finalize is in-place-safe).
        pS  = out;
        pQ  = out + CA;
        cnt = (int*)(out + 2 * CA);
        nPart = 1; use_partials = 0;
        hipMemsetAsync(d_out, 0, (size_t)out_size * sizeof(float), stream);
    }

    hist_kernel <<<64, 256, 0, stream>>>(labels, cnt);
    accum_kernel<<<NCG * NCHUNK, TPB, 0, stream>>>(feat, labels, pS, pQ, use_partials);
    finalize_kernel<<<(int)((CA + 255) / 256), 256, 0, stream>>>(pS, pQ, nPart, cnt, cov, mean, amount, out);
    amount_kernel<<<(C_ + 255) / 256, 256, 0, stream>>>(cnt, amount, out);
}

// Round 2
// 55.603 us; speedup vs baseline: 6.4822x; 6.4822x over previous
//
#include <hip/hip_runtime.h>

constexpr int C_ = 1000;
constexpr int A_ = 512;
constexpr int N_ = 65536;
constexpr int CA_ = C_ * A_;
constexpr float ONE_MINUS_M = 0.2f;   // 1 - MOMENTUM

// ---------- 1) label histogram -> cnt[c] ----------
__global__ __launch_bounds__(256) void hist_kernel(
    const int* __restrict__ labels, int* __restrict__ cnt)
{
    __shared__ int h[C_];
    for (int i = threadIdx.x; i < C_; i += blockDim.x) h[i] = 0;
    __syncthreads();
    for (int i = blockIdx.x * blockDim.x + threadIdx.x; i < N_; i += gridDim.x * blockDim.x)
        atomicAdd(&h[labels[i]], 1);
    __syncthreads();
    for (int i = threadIdx.x; i < C_; i += blockDim.x)
        if (h[i] != 0) atomicAdd(&cnt[i], h[i]);
}

// ---------- 2) exclusive scan of cnt -> base[0..C_], cursor=base ----------
__global__ __launch_bounds__(1024) void scan_kernel(
    const int* __restrict__ cnt, int* __restrict__ base, int* __restrict__ cursor)
{
    __shared__ int s[1024];
    const int t = threadIdx.x;
    const int v = (t < C_) ? cnt[t] : 0;
    s[t] = v;
    __syncthreads();
    // Hillis-Steele inclusive scan
    for (int off = 1; off < 1024; off <<= 1) {
        int x = (t >= off) ? s[t - off] : 0;
        __syncthreads();
        s[t] += x;
        __syncthreads();
    }
    const int incl = s[t];
    if (t < C_) { base[t] = incl - v; cursor[t] = incl - v; }
    if (t == C_ - 1) base[C_] = incl;   // total = N_
}

// ---------- 3) scatter row ids into class buckets ----------
__global__ __launch_bounds__(256) void scatter_kernel(
    const int* __restrict__ labels, int* __restrict__ cursor, int* __restrict__ perm)
{
    const int i = blockIdx.x * blockDim.x + threadIdx.x;
    if (i < N_) {
        const int pos = atomicAdd(&cursor[labels[i]], 1);
        perm[pos] = i;
    }
}

// ---------- 4) per-class gather-reduce + fused EMA finalize ----------
// One block per class; 256 threads x float2 = 512 columns.
__global__ __launch_bounds__(256) void reduce_finalize_kernel(
    const float* __restrict__ feat, const int* __restrict__ base,
    const int* __restrict__ perm, const float* __restrict__ cov,
    const float* __restrict__ mean, const float* __restrict__ amount,
    float* __restrict__ out)
{
    const int c  = blockIdx.x;
    const int b0 = base[c];
    const int b1 = base[c + 1];
    const int cntc = b1 - b0;
    const int t  = threadIdx.x;

    float sx = 0.f, sy = 0.f, qx = 0.f, qy = 0.f;

    int r = 0;
    // 8-row batches: 8 independent coalesced 2KB row loads in flight.
    for (; r + 8 <= cntc; r += 8) {
        int rid[8];
        #pragma unroll
        for (int u = 0; u < 8; ++u) rid[u] = perm[b0 + r + u];
        #pragma unroll
        for (int u = 0; u < 8; ++u) {
            const float2 v = *reinterpret_cast<const float2*>(
                feat + (size_t)rid[u] * A_ + 2 * t);
            sx += v.x; sy += v.y;
            qx = fmaf(v.x, v.x, qx);
            qy = fmaf(v.y, v.y, qy);
        }
    }
    for (; r < cntc; ++r) {
        const int rid = perm[b0 + r];
        const float2 v = *reinterpret_cast<const float2*>(
            feat + (size_t)rid * A_ + 2 * t);
        sx += v.x; sy += v.y;
        qx = fmaf(v.x, v.x, qx);
        qy = fmaf(v.y, v.y, qy);
    }

    // ---- finalize (per class, per column pair) ----
    const float cntf = (float)cntc;
    const float safe = (cntc == 0) ? 1.f : cntf;
    const float avex = sx / safe, avey = sy / safe;
    const float varx = fmaxf(qx / safe - avex * avex, 0.f);
    const float vary = fmaxf(qy / safe - avey * avey, 0.f);

    const float amt   = amount[c];
    const float den   = cntf + amt;
    const float w_raw = (den > 0.f) ? (cntf / den) : 0.f;
    const float w     = (w_raw > 0.f) ? fmaxf(w_raw, ONE_MINUS_M) : 0.f;
    const float omw   = 1.f - w;

    const int idx = c * A_ + 2 * t;
    const float2 m  = *reinterpret_cast<const float2*>(mean + idx);
    const float2 cv = *reinterpret_cast<const float2*>(cov + idx);
    const float dx = m.x - avex, dy = m.y - avey;

    float2 oc, om;
    oc.x = cv.x * omw + varx * w + w * omw * dx * dx;
    oc.y = cv.y * omw + vary * w + w * omw * dy * dy;
    om.x = m.x * omw + avex * w;
    om.y = m.y * omw + avey * w;
    *reinterpret_cast<float2*>(out + idx)       = oc;
    *reinterpret_cast<float2*>(out + CA_ + idx) = om;
    if (t == 0) out[2 * CA_ + c] = amt + cntf;
}

extern "C" void kernel_launch(void* const* d_in, const int* in_sizes, int n_in,
                              void* d_out, int out_size, void* d_ws, size_t ws_size,
                              hipStream_t stream)
{
    const float* feat   = (const float*)d_in[0];
    const int*   labels = (const int*)  d_in[1];
    const float* cov    = (const float*)d_in[2];
    const float* mean   = (const float*)d_in[3];
    const float* amount = (const float*)d_in[4];
    float* out = (float*)d_out;

    // ws layout (ints): cnt[1024] | base[1024] | cursor[1024] | perm[65536]
    // ~274 KB total; proven ws_size >= 33 MB last round (tier-1 partials ran).
    int* cnt    = (int*)d_ws;
    int* base   = cnt + 1024;
    int* cursor = cnt + 2048;
    int* perm   = cnt + 3072;

    hipMemsetAsync(cnt, 0, 1024 * sizeof(int), stream);

    hist_kernel   <<<64, 256, 0, stream>>>(labels, cnt);
    scan_kernel   <<<1, 1024, 0, stream>>>(cnt, base, cursor);
    scatter_kernel<<<(N_ + 255) / 256, 256, 0, stream>>>(labels, cursor, perm);
    reduce_finalize_kernel<<<C_, 256, 0, stream>>>(feat, base, perm, cov, mean, amount, out);
}

// Round 3
// 54.579 us; speedup vs baseline: 6.6037x; 1.0187x over previous
//
#include <hip/hip_runtime.h>

constexpr int C_ = 1000;
constexpr int A_ = 512;
constexpr int N_ = 65536;
constexpr int CA_ = C_ * A_;
constexpr float ONE_MINUS_M = 0.2f;   // 1 - MOMENTUM

// ---------- 1) label histogram -> cnt[c] ----------
__global__ __launch_bounds__(256) void hist_kernel(
    const int* __restrict__ labels, int* __restrict__ cnt)
{
    __shared__ int h[C_];
    for (int i = threadIdx.x; i < C_; i += blockDim.x) h[i] = 0;
    __syncthreads();
    for (int i = blockIdx.x * blockDim.x + threadIdx.x; i < N_; i += gridDim.x * blockDim.x)
        atomicAdd(&h[labels[i]], 1);
    __syncthreads();
    for (int i = threadIdx.x; i < C_; i += blockDim.x)
        if (h[i] != 0) atomicAdd(&cnt[i], h[i]);
}

// ---------- 2) exclusive scan of cnt -> base[0..C_], cursor=base ----------
__global__ __launch_bounds__(1024) void scan_kernel(
    const int* __restrict__ cnt, int* __restrict__ base, int* __restrict__ cursor)
{
    __shared__ int s[1024];
    const int t = threadIdx.x;
    const int v = (t < C_) ? cnt[t] : 0;
    s[t] = v;
    __syncthreads();
    for (int off = 1; off < 1024; off <<= 1) {
        int x = (t >= off) ? s[t - off] : 0;
        __syncthreads();
        s[t] += x;
        __syncthreads();
    }
    const int incl = s[t];
    if (t < C_) { base[t] = incl - v; cursor[t] = incl - v; }
    if (t == C_ - 1) base[C_] = incl;
}

// ---------- 3) scatter row ids into class buckets ----------
__global__ __launch_bounds__(256) void scatter_kernel(
    const int* __restrict__ labels, int* __restrict__ cursor, int* __restrict__ perm)
{
    const int i = blockIdx.x * blockDim.x + threadIdx.x;
    if (i < N_) {
        const int pos = atomicAdd(&cursor[labels[i]], 1);
        perm[pos] = i;
    }
}

// ---------- 4) per-class gather-reduce + fused EMA finalize ----------
// One block per class. 256 threads = 2 row-groups x 128 col-threads (float4).
// 8 rows per batch, next batch's perm prefetched during the FMA phase.
__global__ __launch_bounds__(256) void reduce_finalize_kernel(
    const float* __restrict__ feat, const int* __restrict__ base,
    const int* __restrict__ perm, const float* __restrict__ cov,
    const float* __restrict__ mean, const float* __restrict__ amount,
    float* __restrict__ out)
{
    __shared__ float lred[128 * 8];   // group-1 partials: [col-thread][s4|q4]

    const int c  = blockIdx.x;
    const int b0 = base[c];
    const int cntc = base[c + 1] - b0;
    const int t  = threadIdx.x;
    const int g  = t >> 7;            // row group 0/1
    const int ct = t & 127;           // col thread
    const int cb = ct * 4;            // column base (float4)

    float4 s = {0.f, 0.f, 0.f, 0.f};
    float4 q = {0.f, 0.f, 0.f, 0.f};

    int r = 0;
    int rid[4];
    bool have = (8 <= cntc);
    if (have) {
        #pragma unroll
        for (int u = 0; u < 4; ++u) rid[u] = perm[b0 + 2 * u + g];
    }
    while (have) {
        float4 v[4];
        #pragma unroll
        for (int u = 0; u < 4; ++u)
            v[u] = *reinterpret_cast<const float4*>(feat + (size_t)rid[u] * A_ + cb);

        const int rn = r + 8;
        const bool havn = (rn + 8 <= cntc);
        int nrid[4] = {0, 0, 0, 0};
        if (havn) {
            #pragma unroll
            for (int u = 0; u < 4; ++u) nrid[u] = perm[b0 + rn + 2 * u + g];
        }

        #pragma unroll
        for (int u = 0; u < 4; ++u) {
            s.x += v[u].x; s.y += v[u].y; s.z += v[u].z; s.w += v[u].w;
            q.x = fmaf(v[u].x, v[u].x, q.x);
            q.y = fmaf(v[u].y, v[u].y, q.y);
            q.z = fmaf(v[u].z, v[u].z, q.z);
            q.w = fmaf(v[u].w, v[u].w, q.w);
        }
        #pragma unroll
        for (int u = 0; u < 4; ++u) rid[u] = nrid[u];
        r = rn; have = havn;
    }
    // tail: pairs, then a possible final single row (group 0 only)
    for (; r + 2 <= cntc; r += 2) {
        const int rr = perm[b0 + r + g];
        const float4 v = *reinterpret_cast<const float4*>(feat + (size_t)rr * A_ + cb);
        s.x += v.x; s.y += v.y; s.z += v.z; s.w += v.w;
        q.x = fmaf(v.x, v.x, q.x); q.y = fmaf(v.y, v.y, q.y);
        q.z = fmaf(v.z, v.z, q.z); q.w = fmaf(v.w, v.w, q.w);
    }
    if (r < cntc && g == 0) {
        const int rr = perm[b0 + r];
        const float4 v = *reinterpret_cast<const float4*>(feat + (size_t)rr * A_ + cb);
        s.x += v.x; s.y += v.y; s.z += v.z; s.w += v.w;
        q.x = fmaf(v.x, v.x, q.x); q.y = fmaf(v.y, v.y, q.y);
        q.z = fmaf(v.z, v.z, q.z); q.w = fmaf(v.w, v.w, q.w);
    }

    // cross-group combine
    if (g == 1) {
        float* p = &lred[ct * 8];
        p[0] = s.x; p[1] = s.y; p[2] = s.z; p[3] = s.w;
        p[4] = q.x; p[5] = q.y; p[6] = q.z; p[7] = q.w;
    }
    __syncthreads();
    if (g == 0) {
        const float* p = &lred[ct * 8];
        s.x += p[0]; s.y += p[1]; s.z += p[2]; s.w += p[3];
        q.x += p[4]; q.y += p[5]; q.z += p[6]; q.w += p[7];

        const float cntf = (float)cntc;
        const float safe = (cntc == 0) ? 1.f : cntf;
        const float inv  = 1.f / safe;
        float4 ave, var;
        ave.x = s.x * inv; ave.y = s.y * inv; ave.z = s.z * inv; ave.w = s.w * inv;
        var.x = fmaxf(q.x * inv - ave.x * ave.x, 0.f);
        var.y = fmaxf(q.y * inv - ave.y * ave.y, 0.f);
        var.z = fmaxf(q.z * inv - ave.z * ave.z, 0.f);
        var.w = fmaxf(q.w * inv - ave.w * ave.w, 0.f);

        const float amt   = amount[c];
        const float den   = cntf + amt;
        const float w_raw = (den > 0.f) ? (cntf / den) : 0.f;
        const float w     = (w_raw > 0.f) ? fmaxf(w_raw, ONE_MINUS_M) : 0.f;
        const float omw   = 1.f - w;

        const int idx = c * A_ + cb;
        const float4 m  = *reinterpret_cast<const float4*>(mean + idx);
        const float4 cv = *reinterpret_cast<const float4*>(cov + idx);
        float4 oc, om;
        const float dx = m.x - ave.x, dy = m.y - ave.y,
                    dz = m.z - ave.z, dw = m.w - ave.w;
        oc.x = cv.x * omw + var.x * w + w * omw * dx * dx;
        oc.y = cv.y * omw + var.y * w + w * omw * dy * dy;
        oc.z = cv.z * omw + var.z * w + w * omw * dz * dz;
        oc.w = cv.w * omw + var.w * w + w * omw * dw * dw;
        om.x = m.x * omw + ave.x * w;
        om.y = m.y * omw + ave.y * w;
        om.z = m.z * omw + ave.z * w;
        om.w = m.w * omw + ave.w * w;
        *reinterpret_cast<float4*>(out + idx)       = oc;
        *reinterpret_cast<float4*>(out + CA_ + idx) = om;
        if (ct == 0) out[2 * CA_ + c] = amt + cntf;
    }
}

extern "C" void kernel_launch(void* const* d_in, const int* in_sizes, int n_in,
                              void* d_out, int out_size, void* d_ws, size_t ws_size,
                              hipStream_t stream)
{
    const float* feat   = (const float*)d_in[0];
    const int*   labels = (const int*)  d_in[1];
    const float* cov    = (const float*)d_in[2];
    const float* mean   = (const float*)d_in[3];
    const float* amount = (const float*)d_in[4];
    float* out = (float*)d_out;

    // ws layout (ints): cnt[1024] | base[1024] | cursor[1024] | perm[65536]
    int* cnt    = (int*)d_ws;
    int* base   = cnt + 1024;
    int* cursor = cnt + 2048;
    int* perm   = cnt + 3072;

    hipMemsetAsync(cnt, 0, 1024 * sizeof(int), stream);

    hist_kernel   <<<64, 256, 0, stream>>>(labels, cnt);
    scan_kernel   <<<1, 1024, 0, stream>>>(cnt, base, cursor);
    scatter_kernel<<<(N_ + 255) / 256, 256, 0, stream>>>(labels, cursor, perm);
    reduce_finalize_kernel<<<C_, 256, 0, stream>>>(feat, base, perm, cov, mean, amount, out);
}